// Round 5
// baseline (461.309 us; speedup 1.0000x reference)
//
#include <hip/hip_runtime.h>

#define B_SZ 4
#define SEQ  2048
#define CH   768
#define NH   12
#define HD   64

typedef float f32x4  __attribute__((ext_vector_type(4)));
typedef float f32x16 __attribute__((ext_vector_type(16)));
typedef __bf16 bf16x8 __attribute__((ext_vector_type(8)));
typedef __bf16 bf16x2 __attribute__((ext_vector_type(2)));

#define MFMA16(a,b,c) __builtin_amdgcn_mfma_f32_16x16x32_bf16(a,b,c,0,0,0)
#define MFMA32(a,b,c) __builtin_amdgcn_mfma_f32_32x32x16_bf16(a,b,c,0,0,0)

// scale = 1/sqrt(64) * log2(e)  -> softmax uses exp2
#define QSCALE 0.1803368801111204f

// Compiler-known exp2 (single v_exp_f32 with proper hazard handling).
// R4's inline-asm v_exp_f32 corrupted results (no hazard nops around opaque asm).
#if __has_builtin(__builtin_amdgcn_exp2f)
#define EXP2(x) __builtin_amdgcn_exp2f(x)
#else
#define EXP2(x) exp2f(x)
#endif

__device__ __forceinline__ unsigned pack2(float a, float b) {
    union { bf16x2 v; unsigned u; } p;
    p.v[0] = (__bf16)a; p.v[1] = (__bf16)b;
    return p.u;
}

// async global->LDS, 16B per lane. lds dest must be uniform + lane*16.
__device__ __forceinline__ void lds_dma16(const void* g, void* l) {
    __builtin_amdgcn_global_load_lds(
        (const __attribute__((address_space(1))) void*)g,
        (__attribute__((address_space(3))) void*)(unsigned)(unsigned long long)l,
        16, 0, 0);
}

// ---------------- fp32 -> bf16 convert ----------------
__global__ __launch_bounds__(256) void convert_bf16(const float* __restrict__ src,
                                                    __bf16* __restrict__ dst, int n) {
    int i = (blockIdx.x * 256 + threadIdx.x) * 4;
    if (i >= n) return;
    float4 v = *(const float4*)(src + i);
    union { __bf16 h[4]; uint2 u; } o;
    o.h[0] = (__bf16)v.x; o.h[1] = (__bf16)v.y; o.h[2] = (__bf16)v.z; o.h[3] = (__bf16)v.w;
    *(uint2*)(dst + i) = o.u;
}

// ---------------- 128x128 tile (BK=64) MFMA mainloop: C = A(MxK) * B(NxK)^T ----------------
// LDS layout: row-major [128][64] bf16, 16B chunk c stored at phys chunk c ^ (row&7).
__device__ __forceinline__ void gemm128_loop(const __bf16* __restrict__ A,
                                             const __bf16* __restrict__ Bm,
                                             int K, int rowBlk, int colBlk,
                                             __bf16* As, __bf16* Bs,
                                             f32x4 acc[4][4]) {
    const int tid  = threadIdx.x;
    const int lane = tid & 63, wid = tid >> 6;
    const int quad = lane >> 4, l16 = lane & 15;
    const int wm = wid >> 1, wn = wid & 1;

    f32x4 z = {0.f, 0.f, 0.f, 0.f};
#pragma unroll
    for (int mi = 0; mi < 4; ++mi)
#pragma unroll
        for (int ni = 0; ni < 4; ++ni) acc[mi][ni] = z;

    for (int k0 = 0; k0 < K; k0 += 64) {
        __syncthreads();
#pragma unroll
        for (int i = 0; i < 4; ++i) {
            int s = i * 256 + tid;
            int row = s >> 3, pc = s & 7;
            int lc = pc ^ (row & 7);
            lds_dma16(A  + (size_t)(rowBlk + row) * K + k0 + lc * 8, As + s * 8);
            lds_dma16(Bm + (size_t)(colBlk + row) * K + k0 + lc * 8, Bs + s * 8);
        }
        __syncthreads();

#pragma unroll
        for (int kc = 0; kc < 2; ++kc) {
            bf16x8 af[4], bfr[4];
#pragma unroll
            for (int mi = 0; mi < 4; ++mi) {
                int row = wm * 64 + mi * 16 + l16;
                int pc = (quad + 4 * kc) ^ (row & 7);
                af[mi] = *(const bf16x8*)(As + row * 64 + pc * 8);
            }
#pragma unroll
            for (int ni = 0; ni < 4; ++ni) {
                int row = wn * 64 + ni * 16 + l16;
                int pc = (quad + 4 * kc) ^ (row & 7);
                bfr[ni] = *(const bf16x8*)(Bs + row * 64 + pc * 8);
            }
#pragma unroll
            for (int mi = 0; mi < 4; ++mi)
#pragma unroll
                for (int ni = 0; ni < 4; ++ni)
                    acc[mi][ni] = MFMA16(af[mi], bfr[ni], acc[mi][ni]);
        }
    }
}

// ---------------- QKV GEMM: X(8192x768) @ Wqkv(2304x768)^T, scatter to Q/K/Vt ----------------
__global__ __launch_bounds__(256) void qkv_gemm(const __bf16* __restrict__ Xb,
                                                const __bf16* __restrict__ Wb,
                                                __bf16* __restrict__ Qb,
                                                __bf16* __restrict__ Kb,
                                                __bf16* __restrict__ Vt) {
    __shared__ __bf16 smem[128 * 128];   // 32 KB: mainloop uses first 16 KB; V-epilogue all
    f32x4 acc[4][4];
    const int rowBlk = blockIdx.x * 128, colBlk = blockIdx.y * 128;
    gemm128_loop(Xb, Wb, CH, rowBlk, colBlk, smem, smem + 128 * 64, acc);

    const int tid = threadIdx.x;
    const int lane = tid & 63, wid = tid >> 6;
    const int quad = lane >> 4, l16 = lane & 15, wm = wid >> 1, wn = wid & 1;
    const int b = rowBlk >> 11, n0 = rowBlk & (SEQ - 1);

    if (colBlk < 2 * CH) {
        const int isK = (colBlk >= CH);
#pragma unroll
        for (int mi = 0; mi < 4; ++mi)
#pragma unroll
            for (int ni = 0; ni < 4; ++ni)
#pragma unroll
                for (int r = 0; r < 4; ++r) {
                    int n = n0 + wm * 64 + mi * 16 + quad * 4 + r;
                    int cc = colBlk - (isK ? CH : 0) + wn * 64 + ni * 16 + l16;
                    int h = cc >> 6, d = cc & 63;
                    size_t idx = (size_t)((b * NH + h) * SEQ + n) * HD + d;
                    float v = acc[mi][ni][r];
                    if (isK) Kb[idx] = (__bf16)v;
                    else     Qb[idx] = (__bf16)(v * QSCALE);
                }
    } else {
        // V: transpose through LDS, write V^T coalesced
        const int vblk = colBlk - 2 * CH;
        __syncthreads();
#pragma unroll
        for (int mi = 0; mi < 4; ++mi)
#pragma unroll
            for (int ni = 0; ni < 4; ++ni)
#pragma unroll
                for (int r = 0; r < 4; ++r) {
                    int rl = wm * 64 + mi * 16 + quad * 4 + r;   // n-local
                    int cl = wn * 64 + ni * 16 + l16;            // d-local
                    smem[cl * 128 + (((rl >> 3) ^ (cl & 15)) << 3) + (rl & 7)] =
                        (__bf16)acc[mi][ni][r];
                }
        __syncthreads();
        const int dl = tid >> 1;
        const int d  = vblk + dl;
        const int h  = d >> 6, dd = d & 63;
        const size_t base = (size_t)((b * NH + h) * HD + dd) * SEQ + n0;
#pragma unroll
        for (int j2 = 0; j2 < 8; ++j2) {
            int j = (tid & 1) * 8 + j2;
            uint4 val = *(const uint4*)(smem + dl * 128 + ((j ^ (dl & 15)) << 3));
            *(uint4*)(Vt + base + j * 8) = val;
        }
    }
}

// ---------------- Flash attention v5: double-buffered, single barrier/iter, XCD-pinned heads ----
__global__ __launch_bounds__(256, 3) void flash_attn(const __bf16* __restrict__ Qb,
                                                     const __bf16* __restrict__ Kb,
                                                     const __bf16* __restrict__ Vt,
                                                     __bf16* __restrict__ Ab) {
    __shared__ __bf16 smem[2][2][64 * 64];   // [buf][0=K,1=V] = 32 KB

    const int tid  = threadIdx.x;
    const int lane = tid & 63, wid = tid >> 6;
    const int l32  = lane & 31, half = lane >> 5;

    // XCD-aware decode: blk%8 = XCD (round-robin dispatch); 6 heads per XCD.
    const int lin  = blockIdx.x;              // 0..767
    const int xcd  = lin & 7, idx = lin >> 3; // idx 0..95
    const int bh   = xcd * 6 + (idx >> 4);    // 0..47
    const int qblk = idx & 15;
    const int b    = bh / NH, head = bh - b * NH;

    const int q = qblk * 128 + wid * 32 + l32;

    // Q^T B-fragments (held whole kernel): lane = col q, k-dim = kc*16 + half*8 + j
    bf16x8 qf[4];
#pragma unroll
    for (int kc = 0; kc < 4; ++kc)
        qf[kc] = *(const bf16x8*)(Qb + (size_t)(bh * SEQ + q) * HD + kc * 16 + half * 8);

    f32x16 ot[2];
#pragma unroll
    for (int nd = 0; nd < 2; ++nd)
#pragma unroll
        for (int r = 0; r < 16; ++r) ot[nd][r] = 0.f;
    float l_part = 0.f;

    const __bf16* Kbh = Kb + (size_t)bh * SEQ * HD;
    const __bf16* Vbh = Vt + (size_t)bh * HD * SEQ;

    // stage K+V tile kt into buffer d (16 KB, 4 dma issues)
    const int s_row = tid >> 3, s_pc = tid & 7;
    const int s_lc0 = s_pc ^ (s_row & 7);
    const int s_lc1 = s_pc ^ ((s_row + 32) & 7);
#define STAGE(kt, d)                                                                          \
    do {                                                                                      \
        lds_dma16(Kbh + (size_t)((kt) * 64 + s_row) * HD + s_lc0 * 8, &smem[d][0][tid * 8]);  \
        lds_dma16(Vbh + (size_t)s_row * SEQ + (kt) * 64 + s_lc0 * 8,  &smem[d][1][tid * 8]);  \
        lds_dma16(Kbh + (size_t)((kt) * 64 + s_row + 32) * HD + s_lc1 * 8,                    \
                  &smem[d][0][2048 + tid * 8]);                                               \
        lds_dma16(Vbh + (size_t)(s_row + 32) * SEQ + (kt) * 64 + s_lc1 * 8,                   \
                  &smem[d][1][2048 + tid * 8]);                                               \
    } while (0)

    STAGE(0, 0);

    for (int kb = 0; kb < SEQ / 64; ++kb) {
        const int cur = kb & 1;
        __syncthreads();   // drains own dma (vmcnt) -> buf[cur] ready; prior buf reads done
        const __bf16* Ks = smem[cur][0];
        const __bf16* Vs = smem[cur][1];

        // S^T = K . Q^T : K A-frags from swizzled LDS
        f32x16 st[2];
#pragma unroll
        for (int nb = 0; nb < 2; ++nb) {
#pragma unroll
            for (int r = 0; r < 16; ++r) st[nb][r] = 0.f;
#pragma unroll
            for (int kc = 0; kc < 4; ++kc) {
                int row = nb * 32 + l32;
                int c = kc * 2 + half;
                bf16x8 kf = *(const bf16x8*)(Ks + row * 64 + ((c ^ (row & 7)) << 3));
                st[nb] = MFMA32(kf, qf[kc], st[nb]);
            }
        }

        // V^T fragments for PV, hoisted BEFORE the prefetch so the tail is register-only
        bf16x8 vf[8];
#pragma unroll
        for (int nd = 0; nd < 2; ++nd)
#pragma unroll
            for (int g = 0; g < 4; ++g) {
                int row = nd * 32 + l32;
                int c = g * 2 + half;
                vf[nd * 4 + g] = *(const bf16x8*)(Vs + row * 64 + ((c ^ (row & 7)) << 3));
            }

        // prefetch next tile into the other buffer; stays in flight through the tail
        if (kb + 1 < SEQ / 64) STAGE(kb + 1, cur ^ 1);

        // p = 2^s (Q pre-scaled); all 32 values belong to query q = l32
#pragma unroll
        for (int t = 0; t < 2; ++t)
#pragma unroll
            for (int r = 0; r < 16; ++r) {
                float p = EXP2(st[t][r]);
                st[t][r] = p;
                l_part += p;
            }

        // P^T B-fragments via register exchange (shfl_xor 32)
        bf16x8 pf[4];
#pragma unroll
        for (int t = 0; t < 2; ++t)
#pragma unroll
            for (int c = 0; c < 2; ++c) {
                int kb_ = 8 * c + 4 * half;
                int sb_ = 8 * c + 4 * (1 - half);
                unsigned k0 = pack2(st[t][kb_ + 0], st[t][kb_ + 1]);
                unsigned k1 = pack2(st[t][kb_ + 2], st[t][kb_ + 3]);
                unsigned s0 = pack2(st[t][sb_ + 0], st[t][sb_ + 1]);
                unsigned s1 = pack2(st[t][sb_ + 2], st[t][sb_ + 3]);
                unsigned r0 = (unsigned)__shfl_xor((int)s0, 32, 64);
                unsigned r1 = (unsigned)__shfl_xor((int)s1, 32, 64);
                union { bf16x8 v; unsigned u[4]; } f;
                f.u[0] = half ? r0 : k0;
                f.u[1] = half ? r1 : k1;
                f.u[2] = half ? k0 : r0;
                f.u[3] = half ? k1 : r1;
                pf[t * 2 + c] = f.v;
            }

        // O^T += V^T . P^T  (register-only)
#pragma unroll
        for (int nd = 0; nd < 2; ++nd)
#pragma unroll
            for (int g = 0; g < 4; ++g)
                ot[nd] = MFMA32(vf[nd * 4 + g], pf[g], ot[nd]);
    }

    float l_full = l_part + __shfl_xor(l_part, 32, 64);
    float rinv = 1.f / l_full;

    __syncthreads();   // reuse smem as [128][72] for O transpose
    __bf16 (*Ob)[72] = (__bf16(*)[72])smem;
#pragma unroll
    for (int nd = 0; nd < 2; ++nd)
#pragma unroll
        for (int r = 0; r < 16; ++r) {
            int d = nd * 32 + (r & 3) + 8 * (r >> 2) + 4 * half;
            Ob[wid * 32 + l32][d] = (__bf16)(ot[nd][r] * rinv);
        }
    __syncthreads();
#pragma unroll
    for (int p = 0; p < 4; ++p) {
        int ql = (lane >> 3) + p * 8;
        int c  = (lane & 7) * 8;
        uint4 v = *(const uint4*)(&Ob[wid * 32 + ql][c]);
        *(uint4*)(Ab + (size_t)(b * SEQ + qblk * 128 + wid * 32 + ql) * CH + head * HD + c) = v;
    }
#undef STAGE
}

// ---------------- Projection GEMM: Attn(8192x768) @ proj_w(768x768)^T + bias ----------------
__global__ __launch_bounds__(256) void proj_gemm(const __bf16* __restrict__ Ab,
                                                 const __bf16* __restrict__ Pw,
                                                 const float* __restrict__ bias,
                                                 float* __restrict__ out) {
    __shared__ __bf16 As[128 * 64];
    __shared__ __bf16 Bs[128 * 64];
    f32x4 acc[4][4];
    const int rowBlk = blockIdx.x * 128, colBlk = blockIdx.y * 128;
    gemm128_loop(Ab, Pw, CH, rowBlk, colBlk, As, Bs, acc);

    const int lane = threadIdx.x & 63, wid = threadIdx.x >> 6;
    const int quad = lane >> 4, l16 = lane & 15, wm = wid >> 1, wn = wid & 1;
#pragma unroll
    for (int mi = 0; mi < 4; ++mi)
#pragma unroll
        for (int ni = 0; ni < 4; ++ni)
#pragma unroll
            for (int r = 0; r < 4; ++r) {
                int row = rowBlk + wm * 64 + mi * 16 + quad * 4 + r;
                int col = colBlk + wn * 64 + ni * 16 + l16;
                out[(size_t)row * CH + col] = acc[mi][ni][r] + bias[col];
            }
}

extern "C" void kernel_launch(void* const* d_in, const int* in_sizes, int n_in,
                              void* d_out, int out_size, void* d_ws, size_t ws_size,
                              hipStream_t stream) {
    const float* x      = (const float*)d_in[0];
    const float* qkv_w  = (const float*)d_in[1];
    const float* proj_w = (const float*)d_in[2];
    const float* proj_b = (const float*)d_in[3];
    float* out = (float*)d_out;

    char* ws = (char*)d_ws;
    const size_t nX = (size_t)B_SZ * SEQ * CH;
    const size_t nW = (size_t)3 * CH * CH;
    const size_t nP = (size_t)CH * CH;
    const size_t nQ = (size_t)B_SZ * NH * SEQ * HD;

    __bf16* Xb = (__bf16*)(ws);
    __bf16* Wb = (__bf16*)(ws + 2 * nX);
    __bf16* Pw = (__bf16*)(ws + 2 * (nX + nW));
    __bf16* Qb = (__bf16*)(ws + 2 * (nX + nW + nP));
    __bf16* Kb = (__bf16*)(ws + 2 * (nX + nW + nP + nQ));
    __bf16* Vt = (__bf16*)(ws + 2 * (nX + nW + nP + 2 * nQ));
    __bf16* Ab = (__bf16*)(ws + 2 * (nX + nW + nP + 3 * nQ));

    convert_bf16<<<(int)(nX / 1024), 256, 0, stream>>>(x, Xb, (int)nX);
    convert_bf16<<<(int)(nW / 1024), 256, 0, stream>>>(qkv_w, Wb, (int)nW);
    convert_bf16<<<(int)(nP / 1024), 256, 0, stream>>>(proj_w, Pw, (int)nP);

    qkv_gemm<<<dim3((B_SZ * SEQ) / 128, (3 * CH) / 128), 256, 0, stream>>>(Xb, Wb, Qb, Kb, Vt);

    flash_attn<<<768, 256, 0, stream>>>(Qb, Kb, Vt, Ab);

    proj_gemm<<<dim3((B_SZ * SEQ) / 128, CH / 128), 256, 0, stream>>>(Ab, Pw, proj_b, out);
}

// Round 6
// 226.143 us; speedup vs baseline: 2.0399x; 2.0399x over previous
//
#include <hip/hip_runtime.h>

#define B_SZ 4
#define SEQ  2048
#define CH   768
#define NH   12
#define HD   64

typedef float f32x4  __attribute__((ext_vector_type(4)));
typedef __bf16 bf16x8 __attribute__((ext_vector_type(8)));
typedef __bf16 bf16x2 __attribute__((ext_vector_type(2)));

#define MFMA16(a,b,c) __builtin_amdgcn_mfma_f32_16x16x32_bf16(a,b,c,0,0,0)

// scale = 1/sqrt(64) * log2(e)  -> softmax uses exp2
#define QSCALE 0.1803368801111204f

#if __has_builtin(__builtin_amdgcn_exp2f)
#define EXP2(x) __builtin_amdgcn_exp2f(x)
#else
#define EXP2(x) exp2f(x)
#endif

__device__ __forceinline__ unsigned pack2(float a, float b) {
    union { bf16x2 v; unsigned u; } p;
    p.v[0] = (__bf16)a; p.v[1] = (__bf16)b;
    return p.u;
}

// async global->LDS, 16B per lane. lds dest must be wave-uniform base + lane*16.
__device__ __forceinline__ void lds_dma16(const void* g, void* l) {
    __builtin_amdgcn_global_load_lds(
        (const __attribute__((address_space(1))) void*)g,
        (__attribute__((address_space(3))) void*)(unsigned)(unsigned long long)l,
        16, 0, 0);
}

// ---------------- fp32 -> bf16 convert ----------------
__global__ __launch_bounds__(256) void convert_bf16(const float* __restrict__ src,
                                                    __bf16* __restrict__ dst, int n) {
    int i = (blockIdx.x * 256 + threadIdx.x) * 4;
    if (i >= n) return;
    float4 v = *(const float4*)(src + i);
    union { __bf16 h[4]; uint2 u; } o;
    o.h[0] = (__bf16)v.x; o.h[1] = (__bf16)v.y; o.h[2] = (__bf16)v.z; o.h[3] = (__bf16)v.w;
    *(uint2*)(dst + i) = o.u;
}

// ---------------- 128x128 tile (BK=64) MFMA mainloop: C = A(MxK) * B(NxK)^T ----------------
// LDS layout: row-major [128][64] bf16, 16B chunk c stored at phys chunk c ^ (row&7).
__device__ __forceinline__ void gemm128_loop(const __bf16* __restrict__ A,
                                             const __bf16* __restrict__ Bm,
                                             int K, int rowBlk, int colBlk,
                                             __bf16* As, __bf16* Bs,
                                             f32x4 acc[4][4]) {
    const int tid  = threadIdx.x;
    const int lane = tid & 63, wid = tid >> 6;
    const int quad = lane >> 4, l16 = lane & 15;
    const int wm = wid >> 1, wn = wid & 1;

    f32x4 z = {0.f, 0.f, 0.f, 0.f};
#pragma unroll
    for (int mi = 0; mi < 4; ++mi)
#pragma unroll
        for (int ni = 0; ni < 4; ++ni) acc[mi][ni] = z;

    for (int k0 = 0; k0 < K; k0 += 64) {
        __syncthreads();
#pragma unroll
        for (int i = 0; i < 4; ++i) {
            int s = i * 256 + tid;
            int row = s >> 3, pc = s & 7;
            int lc = pc ^ (row & 7);
            lds_dma16(A  + (size_t)(rowBlk + row) * K + k0 + lc * 8, As + s * 8);
            lds_dma16(Bm + (size_t)(colBlk + row) * K + k0 + lc * 8, Bs + s * 8);
        }
        __syncthreads();

#pragma unroll
        for (int kc = 0; kc < 2; ++kc) {
            bf16x8 af[4], bfr[4];
#pragma unroll
            for (int mi = 0; mi < 4; ++mi) {
                int row = wm * 64 + mi * 16 + l16;
                int pc = (quad + 4 * kc) ^ (row & 7);
                af[mi] = *(const bf16x8*)(As + row * 64 + pc * 8);
            }
#pragma unroll
            for (int ni = 0; ni < 4; ++ni) {
                int row = wn * 64 + ni * 16 + l16;
                int pc = (quad + 4 * kc) ^ (row & 7);
                bfr[ni] = *(const bf16x8*)(Bs + row * 64 + pc * 8);
            }
#pragma unroll
            for (int mi = 0; mi < 4; ++mi)
#pragma unroll
                for (int ni = 0; ni < 4; ++ni)
                    acc[mi][ni] = MFMA16(af[mi], bfr[ni], acc[mi][ni]);
        }
    }
}

// ---------------- QKV GEMM: X(8192x768) @ Wqkv(2304x768)^T, scatter to Q/K/Vt ----------------
__global__ __launch_bounds__(256) void qkv_gemm(const __bf16* __restrict__ Xb,
                                                const __bf16* __restrict__ Wb,
                                                __bf16* __restrict__ Qb,
                                                __bf16* __restrict__ Kb,
                                                __bf16* __restrict__ Vt) {
    __shared__ __bf16 smem[128 * 128];   // 32 KB: mainloop uses first 16 KB; V-epilogue all
    f32x4 acc[4][4];
    const int rowBlk = blockIdx.x * 128, colBlk = blockIdx.y * 128;
    gemm128_loop(Xb, Wb, CH, rowBlk, colBlk, smem, smem + 128 * 64, acc);

    const int tid = threadIdx.x;
    const int lane = tid & 63, wid = tid >> 6;
    const int quad = lane >> 4, l16 = lane & 15, wm = wid >> 1, wn = wid & 1;
    const int b = rowBlk >> 11, n0 = rowBlk & (SEQ - 1);

    if (colBlk < 2 * CH) {
        const int isK = (colBlk >= CH);
#pragma unroll
        for (int mi = 0; mi < 4; ++mi)
#pragma unroll
            for (int ni = 0; ni < 4; ++ni)
#pragma unroll
                for (int r = 0; r < 4; ++r) {
                    int n = n0 + wm * 64 + mi * 16 + quad * 4 + r;
                    int cc = colBlk - (isK ? CH : 0) + wn * 64 + ni * 16 + l16;
                    int h = cc >> 6, d = cc & 63;
                    size_t idx = (size_t)((b * NH + h) * SEQ + n) * HD + d;
                    float v = acc[mi][ni][r];
                    if (isK) Kb[idx] = (__bf16)v;
                    else     Qb[idx] = (__bf16)(v * QSCALE);
                }
    } else {
        // V: transpose through LDS, write V^T coalesced
        const int vblk = colBlk - 2 * CH;
        __syncthreads();
#pragma unroll
        for (int mi = 0; mi < 4; ++mi)
#pragma unroll
            for (int ni = 0; ni < 4; ++ni)
#pragma unroll
                for (int r = 0; r < 4; ++r) {
                    int rl = wm * 64 + mi * 16 + quad * 4 + r;   // n-local
                    int cl = wn * 64 + ni * 16 + l16;            // d-local
                    smem[cl * 128 + (((rl >> 3) ^ (cl & 15)) << 3) + (rl & 7)] =
                        (__bf16)acc[mi][ni][r];
                }
        __syncthreads();
        const int dl = tid >> 1;
        const int d  = vblk + dl;
        const int h  = d >> 6, dd = d & 63;
        const size_t base = (size_t)((b * NH + h) * HD + dd) * SEQ + n0;
#pragma unroll
        for (int j2 = 0; j2 < 8; ++j2) {
            int j = (tid & 1) * 8 + j2;
            uint4 val = *(const uint4*)(smem + dl * 128 + ((j ^ (dl & 15)) << 3));
            *(uint4*)(Vt + base + j * 8) = val;
        }
    }
}

// ---------------- Flash attention v6: MFMA16 S^T, key-permuted P exchange, XCD-pinned ----------
// Block = 4 waves x 16 queries = 64 queries. S^T per wave: 64 keys x 16 q via 4 groups of
// 16x16x32. Key permutation: even group 2kk holds keys kk*32 + quad*8 + r (own j=0..3 of PV
// B-frag); odd group 2kk+1 holds keys kk*32 + (quad^1)*8 + 4 + r (partner's j=4..7, one
// shfl_xor(16)). Zero cndmask, 4 shfl/iter. Scalar per-lane l (all regs belong to q=l16).
__global__ __launch_bounds__(256, 5) void flash_attn(const __bf16* __restrict__ Qb,
                                                     const __bf16* __restrict__ Kb,
                                                     const __bf16* __restrict__ Vt,
                                                     __bf16* __restrict__ Ab) {
    __shared__ __bf16 smem[2][64 * 64];   // [0]=K [key][d], [1]=V^T [d][key]; 16 KB
    __bf16* Ks = smem[0];
    __bf16* Vs = smem[1];

    const int tid  = threadIdx.x;
    const int lane = tid & 63, wid = tid >> 6;
    const int quad = lane >> 4, l16 = lane & 15;

    // XCD-aware decode: blk%8 = XCD; 6 bh x 32 qblk per XCD.
    const int lin  = blockIdx.x;              // 0..1535
    const int xcd  = lin & 7, idx = lin >> 3; // idx 0..191
    const int bh   = xcd * 6 + (idx >> 5);    // 0..47
    const int qblk = idx & 31;                // 0..31
    const int b    = bh / NH, head = bh - b * NH;

    const int q = qblk * 64 + wid * 16 + l16;

    // Q^T B-frags (held whole kernel): lane n=l16=q, k(d) = kcd*32 + quad*8 + j
    bf16x8 qf[2];
#pragma unroll
    for (int kcd = 0; kcd < 2; ++kcd)
        qf[kcd] = *(const bf16x8*)(Qb + (size_t)(bh * SEQ + q) * HD + kcd * 32 + quad * 8);

    // key-permutation row offsets for the S A-frag (lane is MFMA row m = l16)
    const int key_e = ((l16 >> 2) << 3) + (l16 & 3);            // even groups
    const int key_o = ((((l16 >> 2) ^ 1)) << 3) + 4 + (l16 & 3); // odd groups

    f32x4 ot[4];
    f32x4 z = {0.f, 0.f, 0.f, 0.f};
#pragma unroll
    for (int dg = 0; dg < 4; ++dg) ot[dg] = z;
    float l_part = 0.f;

    const __bf16* Kbh = Kb + (size_t)bh * SEQ * HD;
    const __bf16* Vbh = Vt + (size_t)bh * HD * SEQ;

    const int s_row = tid >> 3, s_pc = tid & 7;
    const int s_lc0 = s_pc ^ (s_row & 7);
    const int s_lc1 = s_pc ^ ((s_row + 32) & 7);

    for (int kb = 0; kb < SEQ / 64; ++kb) {
        const int kbase = kb * 64;
        __syncthreads();   // prior-iteration LDS readers done
        // stage K (8 KB) + V^T (8 KB), swizzled chunks, async DMA
        lds_dma16(Kbh + (size_t)(kbase + s_row) * HD + s_lc0 * 8,      Ks + tid * 8);
        lds_dma16(Kbh + (size_t)(kbase + s_row + 32) * HD + s_lc1 * 8, Ks + 2048 + tid * 8);
        lds_dma16(Vbh + (size_t)s_row * SEQ + kbase + s_lc0 * 8,       Vs + tid * 8);
        lds_dma16(Vbh + (size_t)(s_row + 32) * SEQ + kbase + s_lc1 * 8, Vs + 2048 + tid * 8);
        __syncthreads();   // drains dma

        // S^T groups: st[g][r] = S^T[key(g,quad,r)][q=l16]
        f32x4 st[4];
#pragma unroll
        for (int g = 0; g < 4; ++g) {
            st[g] = z;
            const int key = ((g >> 1) << 5) + ((g & 1) ? key_o : key_e);
#pragma unroll
            for (int kcd = 0; kcd < 2; ++kcd) {
                int c8 = quad + (kcd << 2);
                bf16x8 kf = *(const bf16x8*)(Ks + key * 64 + ((c8 ^ (key & 7)) << 3));
                st[g] = MFMA16(kf, qf[kcd], st[g]);
            }
        }

        // p = 2^s; all 16 regs belong to query q=l16 -> scalar l
#pragma unroll
        for (int g = 0; g < 4; ++g)
#pragma unroll
            for (int r = 0; r < 4; ++r) {
                float p = EXP2(st[g][r]);
                st[g][r] = p;
                l_part += p;
            }

        // P^T B-frags: own even group = j0..3, partner's odd group = j4..7
        bf16x8 pf[2];
#pragma unroll
        for (int kk = 0; kk < 2; ++kk) {
            unsigned w0 = pack2(st[2 * kk][0], st[2 * kk][1]);
            unsigned w1 = pack2(st[2 * kk][2], st[2 * kk][3]);
            unsigned x0 = pack2(st[2 * kk + 1][0], st[2 * kk + 1][1]);
            unsigned x1 = pack2(st[2 * kk + 1][2], st[2 * kk + 1][3]);
            unsigned w2 = (unsigned)__shfl_xor((int)x0, 16, 64);
            unsigned w3 = (unsigned)__shfl_xor((int)x1, 16, 64);
            union { bf16x8 v; unsigned u[4]; } f;
            f.u[0] = w0; f.u[1] = w1; f.u[2] = w2; f.u[3] = w3;
            pf[kk] = f.v;
        }

        // O^T += V^T . P^T : A = V^T[d=dg*16+l16][k = kk*32 + quad*8 + j]
#pragma unroll
        for (int dg = 0; dg < 4; ++dg)
#pragma unroll
            for (int kk = 0; kk < 2; ++kk) {
                int row = (dg << 4) + l16;
                int c8 = quad + (kk << 2);
                bf16x8 vf = *(const bf16x8*)(Vs + row * 64 + ((c8 ^ (row & 7)) << 3));
                ot[dg] = MFMA16(vf, pf[kk], ot[dg]);
            }
    }

    // l(q) spread across the 4 quads holding q=l16
    l_part += __shfl_xor(l_part, 16, 64);
    l_part += __shfl_xor(l_part, 32, 64);
    const float rinv = 1.f / l_part;

    __syncthreads();   // reuse smem as [64][72] for O transpose
    __bf16 (*Ob)[72] = (__bf16(*)[72])&smem[0][0];
#pragma unroll
    for (int dg = 0; dg < 4; ++dg)
#pragma unroll
        for (int r = 0; r < 4; ++r) {
            int d = (dg << 4) + (quad << 2) + r;
            Ob[wid * 16 + l16][d] = (__bf16)(ot[dg][r] * rinv);
        }
    __syncthreads();
    {
        const int ql = tid >> 2, c0 = (tid & 3) * 16;
        uint4 v0 = *(const uint4*)(&Ob[ql][c0]);
        uint4 v1 = *(const uint4*)(&Ob[ql][c0 + 8]);
        __bf16* dst = Ab + (size_t)(b * SEQ + qblk * 64 + ql) * CH + head * HD + c0;
        *(uint4*)(dst)     = v0;
        *(uint4*)(dst + 8) = v1;
    }
}

// ---------------- Projection GEMM: Attn(8192x768) @ proj_w(768x768)^T + bias ----------------
__global__ __launch_bounds__(256) void proj_gemm(const __bf16* __restrict__ Ab,
                                                 const __bf16* __restrict__ Pw,
                                                 const float* __restrict__ bias,
                                                 float* __restrict__ out) {
    __shared__ __bf16 As[128 * 64];
    __shared__ __bf16 Bs[128 * 64];
    f32x4 acc[4][4];
    const int rowBlk = blockIdx.x * 128, colBlk = blockIdx.y * 128;
    gemm128_loop(Ab, Pw, CH, rowBlk, colBlk, As, Bs, acc);

    const int lane = threadIdx.x & 63, wid = threadIdx.x >> 6;
    const int quad = lane >> 4, l16 = lane & 15, wm = wid >> 1, wn = wid & 1;
#pragma unroll
    for (int mi = 0; mi < 4; ++mi)
#pragma unroll
        for (int ni = 0; ni < 4; ++ni)
#pragma unroll
            for (int r = 0; r < 4; ++r) {
                int row = rowBlk + wm * 64 + mi * 16 + quad * 4 + r;
                int col = colBlk + wn * 64 + ni * 16 + l16;
                out[(size_t)row * CH + col] = acc[mi][ni][r] + bias[col];
            }
}

extern "C" void kernel_launch(void* const* d_in, const int* in_sizes, int n_in,
                              void* d_out, int out_size, void* d_ws, size_t ws_size,
                              hipStream_t stream) {
    const float* x      = (const float*)d_in[0];
    const float* qkv_w  = (const float*)d_in[1];
    const float* proj_w = (const float*)d_in[2];
    const float* proj_b = (const float*)d_in[3];
    float* out = (float*)d_out;

    char* ws = (char*)d_ws;
    const size_t nX = (size_t)B_SZ * SEQ * CH;
    const size_t nW = (size_t)3 * CH * CH;
    const size_t nP = (size_t)CH * CH;
    const size_t nQ = (size_t)B_SZ * NH * SEQ * HD;

    __bf16* Xb = (__bf16*)(ws);
    __bf16* Wb = (__bf16*)(ws + 2 * nX);
    __bf16* Pw = (__bf16*)(ws + 2 * (nX + nW));
    __bf16* Qb = (__bf16*)(ws + 2 * (nX + nW + nP));
    __bf16* Kb = (__bf16*)(ws + 2 * (nX + nW + nP + nQ));
    __bf16* Vt = (__bf16*)(ws + 2 * (nX + nW + nP + 2 * nQ));
    __bf16* Ab = (__bf16*)(ws + 2 * (nX + nW + nP + 3 * nQ));

    convert_bf16<<<(int)(nX / 1024), 256, 0, stream>>>(x, Xb, (int)nX);
    convert_bf16<<<(int)(nW / 1024), 256, 0, stream>>>(qkv_w, Wb, (int)nW);
    convert_bf16<<<(int)(nP / 1024), 256, 0, stream>>>(proj_w, Pw, (int)nP);

    qkv_gemm<<<dim3((B_SZ * SEQ) / 128, (3 * CH) / 128), 256, 0, stream>>>(Xb, Wb, Qb, Kb, Vt);

    flash_attn<<<1536, 256, 0, stream>>>(Qb, Kb, Vt, Ab);

    proj_gemm<<<dim3((B_SZ * SEQ) / 128, CH / 128), 256, 0, stream>>>(Ab, Pw, proj_b, out);
}

// Round 8
// 215.549 us; speedup vs baseline: 2.1402x; 1.0491x over previous
//
#include <hip/hip_runtime.h>

#define B_SZ 4
#define SEQ  2048
#define CH   768
#define NH   12
#define HD   64

typedef float f32x4  __attribute__((ext_vector_type(4)));
typedef __bf16 bf16x8 __attribute__((ext_vector_type(8)));
typedef __bf16 bf16x2 __attribute__((ext_vector_type(2)));

#define MFMA16(a,b,c) __builtin_amdgcn_mfma_f32_16x16x32_bf16(a,b,c,0,0,0)

// scale = 1/sqrt(64) * log2(e)  -> softmax uses exp2
#define QSCALE 0.1803368801111204f

#if __has_builtin(__builtin_amdgcn_exp2f)
#define EXP2(x) __builtin_amdgcn_exp2f(x)
#else
#define EXP2(x) exp2f(x)
#endif

// flash LDS swizzle: row*128B is bank-invariant; plain row&7 left keys {k,k+8,k+16,k+24}
// on identical banks (4-way conflict, 6.4M cycles in R6). Spread bit 3 in too.
#define SWZ(row) (((row) ^ ((row) >> 3)) & 7)

__device__ __forceinline__ unsigned pack2(float a, float b) {
    union { bf16x2 v; unsigned u; } p;
    p.v[0] = (__bf16)a; p.v[1] = (__bf16)b;
    return p.u;
}

// async global->LDS, 16B per lane. lds dest must be wave-uniform base + lane*16.
__device__ __forceinline__ void lds_dma16(const void* g, void* l) {
    __builtin_amdgcn_global_load_lds(
        (const __attribute__((address_space(1))) void*)g,
        (__attribute__((address_space(3))) void*)(unsigned)(unsigned long long)l,
        16, 0, 0);
}

// ---------------- fp32 -> bf16 convert ----------------
__global__ __launch_bounds__(256) void convert_bf16(const float* __restrict__ src,
                                                    __bf16* __restrict__ dst, int n) {
    int i = (blockIdx.x * 256 + threadIdx.x) * 4;
    if (i >= n) return;
    float4 v = *(const float4*)(src + i);
    union { __bf16 h[4]; uint2 u; } o;
    o.h[0] = (__bf16)v.x; o.h[1] = (__bf16)v.y; o.h[2] = (__bf16)v.z; o.h[3] = (__bf16)v.w;
    *(uint2*)(dst + i) = o.u;
}

// ---------------- 128x128 tile (BK=64) MFMA mainloop: C = A(MxK) * B(NxK)^T ----------------
// LDS layout: row-major [128][64] bf16, 16B chunk c stored at phys chunk c ^ (row&7).
__device__ __forceinline__ void gemm128_loop(const __bf16* __restrict__ A,
                                             const __bf16* __restrict__ Bm,
                                             int K, int rowBlk, int colBlk,
                                             __bf16* As, __bf16* Bs,
                                             f32x4 acc[4][4]) {
    const int tid  = threadIdx.x;
    const int lane = tid & 63, wid = tid >> 6;
    const int quad = lane >> 4, l16 = lane & 15;
    const int wm = wid >> 1, wn = wid & 1;

    f32x4 z = {0.f, 0.f, 0.f, 0.f};
#pragma unroll
    for (int mi = 0; mi < 4; ++mi)
#pragma unroll
        for (int ni = 0; ni < 4; ++ni) acc[mi][ni] = z;

    for (int k0 = 0; k0 < K; k0 += 64) {
        __syncthreads();
#pragma unroll
        for (int i = 0; i < 4; ++i) {
            int s = i * 256 + tid;
            int row = s >> 3, pc = s & 7;
            int lc = pc ^ (row & 7);
            lds_dma16(A  + (size_t)(rowBlk + row) * K + k0 + lc * 8, As + s * 8);
            lds_dma16(Bm + (size_t)(colBlk + row) * K + k0 + lc * 8, Bs + s * 8);
        }
        __syncthreads();

#pragma unroll
        for (int kc = 0; kc < 2; ++kc) {
            bf16x8 af[4], bfr[4];
#pragma unroll
            for (int mi = 0; mi < 4; ++mi) {
                int row = wm * 64 + mi * 16 + l16;
                int pc = (quad + 4 * kc) ^ (row & 7);
                af[mi] = *(const bf16x8*)(As + row * 64 + pc * 8);
            }
#pragma unroll
            for (int ni = 0; ni < 4; ++ni) {
                int row = wn * 64 + ni * 16 + l16;
                int pc = (quad + 4 * kc) ^ (row & 7);
                bfr[ni] = *(const bf16x8*)(Bs + row * 64 + pc * 8);
            }
#pragma unroll
            for (int mi = 0; mi < 4; ++mi)
#pragma unroll
                for (int ni = 0; ni < 4; ++ni)
                    acc[mi][ni] = MFMA16(af[mi], bfr[ni], acc[mi][ni]);
        }
    }
}

// ---------------- QKV GEMM: X(8192x768) @ Wqkv(2304x768)^T, scatter to Q/K/Vt ----------------
__global__ __launch_bounds__(256) void qkv_gemm(const __bf16* __restrict__ Xb,
                                                const __bf16* __restrict__ Wb,
                                                __bf16* __restrict__ Qb,
                                                __bf16* __restrict__ Kb,
                                                __bf16* __restrict__ Vt) {
    __shared__ __bf16 smem[128 * 128];   // 32 KB: mainloop uses first 16 KB; V-epilogue all
    f32x4 acc[4][4];
    const int rowBlk = blockIdx.x * 128, colBlk = blockIdx.y * 128;
    gemm128_loop(Xb, Wb, CH, rowBlk, colBlk, smem, smem + 128 * 64, acc);

    const int tid = threadIdx.x;
    const int lane = tid & 63, wid = tid >> 6;
    const int quad = lane >> 4, l16 = lane & 15, wm = wid >> 1, wn = wid & 1;
    const int b = rowBlk >> 11, n0 = rowBlk & (SEQ - 1);

    if (colBlk < 2 * CH) {
        const int isK = (colBlk >= CH);
#pragma unroll
        for (int mi = 0; mi < 4; ++mi)
#pragma unroll
            for (int ni = 0; ni < 4; ++ni)
#pragma unroll
                for (int r = 0; r < 4; ++r) {
                    int n = n0 + wm * 64 + mi * 16 + quad * 4 + r;
                    int cc = colBlk - (isK ? CH : 0) + wn * 64 + ni * 16 + l16;
                    int h = cc >> 6, d = cc & 63;
                    size_t idx = (size_t)((b * NH + h) * SEQ + n) * HD + d;
                    float v = acc[mi][ni][r];
                    if (isK) Kb[idx] = (__bf16)v;
                    else     Qb[idx] = (__bf16)(v * QSCALE);
                }
    } else {
        // V: transpose through LDS, write V^T coalesced
        const int vblk = colBlk - 2 * CH;
        __syncthreads();
#pragma unroll
        for (int mi = 0; mi < 4; ++mi)
#pragma unroll
            for (int ni = 0; ni < 4; ++ni)
#pragma unroll
                for (int r = 0; r < 4; ++r) {
                    int rl = wm * 64 + mi * 16 + quad * 4 + r;   // n-local
                    int cl = wn * 64 + ni * 16 + l16;            // d-local
                    smem[cl * 128 + (((rl >> 3) ^ (cl & 15)) << 3) + (rl & 7)] =
                        (__bf16)acc[mi][ni][r];
                }
        __syncthreads();
        const int dl = tid >> 1;
        const int d  = vblk + dl;
        const int h  = d >> 6, dd = d & 63;
        const size_t base = (size_t)((b * NH + h) * HD + dd) * SEQ + n0;
#pragma unroll
        for (int j2 = 0; j2 < 8; ++j2) {
            int j = (tid & 1) * 8 + j2;
            uint4 val = *(const uint4*)(smem + dl * 128 + ((j ^ (dl & 15)) << 3));
            *(uint4*)(Vt + base + j * 8) = val;
        }
    }
}

// ---------------- Flash attention v8: R6 structure + SWZ fix + 2 q-tiles per wave -----------
// Block = 4 waves, 128 queries (two 16-q tiles per wave sharing every K/V fragment).
// R6's proven dual-barrier staging (no double-buffer, no hoisted fragment arrays).
__global__ __launch_bounds__(256, 3) void flash_attn(const __bf16* __restrict__ Qb,
                                                     const __bf16* __restrict__ Kb,
                                                     const __bf16* __restrict__ Vt,
                                                     __bf16* __restrict__ Ab) {
    __shared__ __bf16 smem[9216];        // loop: K=smem[0..4095], V^T=smem[4096..8191] (16 KB);
                                         // epilogue reuses as [128][72] (18 KB)
    __bf16* Ks = smem;
    __bf16* Vs = smem + 4096;

    const int tid  = threadIdx.x;
    const int lane = tid & 63, wid = tid >> 6;
    const int quad = lane >> 4, l16 = lane & 15;

    // XCD-aware decode: blk%8 = XCD; 6 bh x 16 qblk per XCD.
    const int lin  = blockIdx.x;              // 0..767
    const int xcd  = lin & 7, idx = lin >> 3; // idx 0..95
    const int bh   = xcd * 6 + (idx >> 4);    // 0..47
    const int qblk = idx & 15;                // 0..15 (128 queries each)
    const int b    = bh / NH, head = bh - b * NH;

    const int qA = qblk * 128 + wid * 16 + l16;
    const int qB = qA + 64;

    // Q^T B-frags (held whole kernel): lane n=l16=q, k(d) = kcd*32 + quad*8 + j
    bf16x8 qfA[2], qfB[2];
#pragma unroll
    for (int kcd = 0; kcd < 2; ++kcd) {
        qfA[kcd] = *(const bf16x8*)(Qb + (size_t)(bh * SEQ + qA) * HD + kcd * 32 + quad * 8);
        qfB[kcd] = *(const bf16x8*)(Qb + (size_t)(bh * SEQ + qB) * HD + kcd * 32 + quad * 8);
    }

    // key permutation (even/odd groups) for zero-cndmask P exchange
    const int key_e = ((l16 >> 2) << 3) + (l16 & 3);
    const int key_o = ((((l16 >> 2) ^ 1)) << 3) + 4 + (l16 & 3);

    f32x4 otA[4], otB[4];
    f32x4 z = {0.f, 0.f, 0.f, 0.f};
#pragma unroll
    for (int dg = 0; dg < 4; ++dg) { otA[dg] = z; otB[dg] = z; }
    float lA = 0.f, lB = 0.f;

    const __bf16* Kbh = Kb + (size_t)bh * SEQ * HD;
    const __bf16* Vbh = Vt + (size_t)bh * HD * SEQ;

    const int s_row = tid >> 3, s_pc = tid & 7;
    const int s_lc0 = s_pc ^ SWZ(s_row);
    const int s_lc1 = s_pc ^ SWZ(s_row + 32);

    for (int kb = 0; kb < SEQ / 64; ++kb) {
        const int kbase = kb * 64;
        __syncthreads();   // prior-iteration LDS readers done
        lds_dma16(Kbh + (size_t)(kbase + s_row) * HD + s_lc0 * 8,       Ks + tid * 8);
        lds_dma16(Kbh + (size_t)(kbase + s_row + 32) * HD + s_lc1 * 8,  Ks + 2048 + tid * 8);
        lds_dma16(Vbh + (size_t)s_row * SEQ + kbase + s_lc0 * 8,        Vs + tid * 8);
        lds_dma16(Vbh + (size_t)(s_row + 32) * SEQ + kbase + s_lc1 * 8, Vs + 2048 + tid * 8);
        __syncthreads();   // drains dma

        // S^T for both q-tiles; each K fragment feeds 2 MFMAs
        f32x4 stA[4], stB[4];
#pragma unroll
        for (int g = 0; g < 4; ++g) { stA[g] = z; stB[g] = z; }
#pragma unroll
        for (int g = 0; g < 4; ++g) {
            const int key = ((g >> 1) << 5) + ((g & 1) ? key_o : key_e);
#pragma unroll
            for (int kcd = 0; kcd < 2; ++kcd) {
                int c8 = quad + (kcd << 2);
                bf16x8 kf = *(const bf16x8*)(Ks + key * 64 + ((c8 ^ SWZ(key)) << 3));
                stA[g] = MFMA16(kf, qfA[kcd], stA[g]);
                stB[g] = MFMA16(kf, qfB[kcd], stB[g]);
            }
        }

        // exp + pack/exchange, tile A then tile B
        bf16x8 pfA[2], pfB[2];
#pragma unroll
        for (int g = 0; g < 4; ++g)
#pragma unroll
            for (int r = 0; r < 4; ++r) {
                float p = EXP2(stA[g][r]);
                stA[g][r] = p;
                lA += p;
            }
#pragma unroll
        for (int kk = 0; kk < 2; ++kk) {
            unsigned w0 = pack2(stA[2 * kk][0], stA[2 * kk][1]);
            unsigned w1 = pack2(stA[2 * kk][2], stA[2 * kk][3]);
            unsigned x0 = pack2(stA[2 * kk + 1][0], stA[2 * kk + 1][1]);
            unsigned x1 = pack2(stA[2 * kk + 1][2], stA[2 * kk + 1][3]);
            unsigned w2 = (unsigned)__shfl_xor((int)x0, 16, 64);
            unsigned w3 = (unsigned)__shfl_xor((int)x1, 16, 64);
            union { bf16x8 v; unsigned u[4]; } f;
            f.u[0] = w0; f.u[1] = w1; f.u[2] = w2; f.u[3] = w3;
            pfA[kk] = f.v;
        }
#pragma unroll
        for (int g = 0; g < 4; ++g)
#pragma unroll
            for (int r = 0; r < 4; ++r) {
                float p = EXP2(stB[g][r]);
                stB[g][r] = p;
                lB += p;
            }
#pragma unroll
        for (int kk = 0; kk < 2; ++kk) {
            unsigned w0 = pack2(stB[2 * kk][0], stB[2 * kk][1]);
            unsigned w1 = pack2(stB[2 * kk][2], stB[2 * kk][3]);
            unsigned x0 = pack2(stB[2 * kk + 1][0], stB[2 * kk + 1][1]);
            unsigned x1 = pack2(stB[2 * kk + 1][2], stB[2 * kk + 1][3]);
            unsigned w2 = (unsigned)__shfl_xor((int)x0, 16, 64);
            unsigned w3 = (unsigned)__shfl_xor((int)x1, 16, 64);
            union { bf16x8 v; unsigned u[4]; } f;
            f.u[0] = w0; f.u[1] = w1; f.u[2] = w2; f.u[3] = w3;
            pfB[kk] = f.v;
        }

        // O^T += V^T . P^T : each V fragment (read inline, once) feeds both tiles
#pragma unroll
        for (int dg = 0; dg < 4; ++dg)
#pragma unroll
            for (int kk = 0; kk < 2; ++kk) {
                int row = (dg << 4) + l16;
                int c8 = quad + (kk << 2);
                bf16x8 vf = *(const bf16x8*)(Vs + row * 64 + ((c8 ^ SWZ(row)) << 3));
                otA[dg] = MFMA16(vf, pfA[kk], otA[dg]);
                otB[dg] = MFMA16(vf, pfB[kk], otB[dg]);
            }
    }

    lA += __shfl_xor(lA, 16, 64);
    lA += __shfl_xor(lA, 32, 64);
    lB += __shfl_xor(lB, 16, 64);
    lB += __shfl_xor(lB, 32, 64);
    const float rA = 1.f / lA, rB = 1.f / lB;

    __syncthreads();   // reuse smem as [128][72] for O transpose
    __bf16 (*Ob)[72] = (__bf16(*)[72])smem;
#pragma unroll
    for (int dg = 0; dg < 4; ++dg)
#pragma unroll
        for (int r = 0; r < 4; ++r) {
            int d = (dg << 4) + (quad << 2) + r;
            Ob[wid * 16 + l16][d]      = (__bf16)(otA[dg][r] * rA);
            Ob[64 + wid * 16 + l16][d] = (__bf16)(otB[dg][r] * rB);
        }
    __syncthreads();
    {
        const int row = tid >> 1, c0 = (tid & 1) * 32;
        __bf16* dst = Ab + (size_t)(b * SEQ + qblk * 128 + row) * CH + head * HD + c0;
#pragma unroll
        for (int j = 0; j < 4; ++j)
            *(uint4*)(dst + j * 8) = *(const uint4*)(&Ob[row][c0 + j * 8]);
    }
}

// ---------------- Projection GEMM: Attn(8192x768) @ proj_w(768x768)^T + bias ----------------
__global__ __launch_bounds__(256) void proj_gemm(const __bf16* __restrict__ Ab,
                                                 const __bf16* __restrict__ Pw,
                                                 const float* __restrict__ bias,
                                                 float* __restrict__ out) {
    __shared__ __bf16 As[128 * 64];
    __shared__ __bf16 Bs[128 * 64];
    f32x4 acc[4][4];
    const int rowBlk = blockIdx.x * 128, colBlk = blockIdx.y * 128;
    gemm128_loop(Ab, Pw, CH, rowBlk, colBlk, As, Bs, acc);

    const int lane = threadIdx.x & 63, wid = threadIdx.x >> 6;
    const int quad = lane >> 4, l16 = lane & 15, wm = wid >> 1, wn = wid & 1;
#pragma unroll
    for (int mi = 0; mi < 4; ++mi)
#pragma unroll
        for (int ni = 0; ni < 4; ++ni)
#pragma unroll
            for (int r = 0; r < 4; ++r) {
                int row = rowBlk + wm * 64 + mi * 16 + quad * 4 + r;
                int col = colBlk + wn * 64 + ni * 16 + l16;
                out[(size_t)row * CH + col] = acc[mi][ni][r] + bias[col];
            }
}

extern "C" void kernel_launch(void* const* d_in, const int* in_sizes, int n_in,
                              void* d_out, int out_size, void* d_ws, size_t ws_size,
                              hipStream_t stream) {
    const float* x      = (const float*)d_in[0];
    const float* qkv_w  = (const float*)d_in[1];
    const float* proj_w = (const float*)d_in[2];
    const float* proj_b = (const float*)d_in[3];
    float* out = (float*)d_out;

    char* ws = (char*)d_ws;
    const size_t nX = (size_t)B_SZ * SEQ * CH;
    const size_t nW = (size_t)3 * CH * CH;
    const size_t nP = (size_t)CH * CH;
    const size_t nQ = (size_t)B_SZ * NH * SEQ * HD;

    __bf16* Xb = (__bf16*)(ws);
    __bf16* Wb = (__bf16*)(ws + 2 * nX);
    __bf16* Pw = (__bf16*)(ws + 2 * (nX + nW));
    __bf16* Qb = (__bf16*)(ws + 2 * (nX + nW + nP));
    __bf16* Kb = (__bf16*)(ws + 2 * (nX + nW + nP + nQ));
    __bf16* Vt = (__bf16*)(ws + 2 * (nX + nW + nP + 2 * nQ));
    __bf16* Ab = (__bf16*)(ws + 2 * (nX + nW + nP + 3 * nQ));

    convert_bf16<<<(int)(nX / 1024), 256, 0, stream>>>(x, Xb, (int)nX);
    convert_bf16<<<(int)(nW / 1024), 256, 0, stream>>>(qkv_w, Wb, (int)nW);
    convert_bf16<<<(int)(nP / 1024), 256, 0, stream>>>(proj_w, Pw, (int)nP);

    qkv_gemm<<<dim3((B_SZ * SEQ) / 128, (3 * CH) / 128), 256, 0, stream>>>(Xb, Wb, Qb, Kb, Vt);

    flash_attn<<<768, 256, 0, stream>>>(Qb, Kb, Vt, Ab);

    proj_gemm<<<dim3((B_SZ * SEQ) / 128, CH / 128), 256, 0, stream>>>(Ab, Pw, proj_b, out);
}

// Round 9
// 210.283 us; speedup vs baseline: 2.1937x; 1.0250x over previous
//
#include <hip/hip_runtime.h>

#define B_SZ 4
#define SEQ  2048
#define CH   768
#define NH   12
#define HD   64

typedef float f32x4  __attribute__((ext_vector_type(4)));
typedef __bf16 bf16x8 __attribute__((ext_vector_type(8)));
typedef __bf16 bf16x2 __attribute__((ext_vector_type(2)));

#define MFMA16(a,b,c) __builtin_amdgcn_mfma_f32_16x16x32_bf16(a,b,c,0,0,0)

// scale = 1/sqrt(64) * log2(e)  -> softmax uses exp2
#define QSCALE 0.1803368801111204f

#if __has_builtin(__builtin_amdgcn_exp2f)
#define EXP2(x) __builtin_amdgcn_exp2f(x)
#else
#define EXP2(x) exp2f(x)
#endif

// flash LDS swizzle (kept from R8; conflict counter proved layout-insensitive, not a lever)
#define SWZ(row) (((row) ^ ((row) >> 3)) & 7)

__device__ __forceinline__ unsigned pack2(float a, float b) {
    union { bf16x2 v; unsigned u; } p;
    p.v[0] = (__bf16)a; p.v[1] = (__bf16)b;
    return p.u;
}

// async global->LDS, 16B per lane. lds dest must be wave-uniform base + lane*16.
__device__ __forceinline__ void lds_dma16(const void* g, void* l) {
    __builtin_amdgcn_global_load_lds(
        (const __attribute__((address_space(1))) void*)g,
        (__attribute__((address_space(3))) void*)(unsigned)(unsigned long long)l,
        16, 0, 0);
}

// ---------------- fused fp32 -> bf16 convert (x | qkv_w | proj_w in one launch) ------------
#define NBLK_X  6144   // 6291456 / 1024
#define NBLK_W  1728   // 1769472 / 1024
#define NBLK_P   576   //  589824 / 1024
__global__ __launch_bounds__(256) void convert_all(const float* __restrict__ x,
                                                   const float* __restrict__ w,
                                                   const float* __restrict__ p,
                                                   __bf16* __restrict__ ox,
                                                   __bf16* __restrict__ ow,
                                                   __bf16* __restrict__ op) {
    int blk = blockIdx.x;
    const float* src;
    __bf16* dst;
    int base;
    if (blk < NBLK_X)               { src = x; dst = ox; base = blk; }
    else if (blk < NBLK_X + NBLK_W) { src = w; dst = ow; base = blk - NBLK_X; }
    else                            { src = p; dst = op; base = blk - NBLK_X - NBLK_W; }
    int i = (base * 256 + threadIdx.x) * 4;
    float4 v = *(const float4*)(src + i);
    union { __bf16 h[4]; uint2 u; } o;
    o.h[0] = (__bf16)v.x; o.h[1] = (__bf16)v.y; o.h[2] = (__bf16)v.z; o.h[3] = (__bf16)v.w;
    *(uint2*)(dst + i) = o.u;
}

// ---------------- 128x128 tile (BK=64) MFMA mainloop: C = A(MxK) * B(NxK)^T ----------------
// LDS layout: row-major [128][64] bf16, 16B chunk c stored at phys chunk c ^ (row&7).
__device__ __forceinline__ void gemm128_loop(const __bf16* __restrict__ A,
                                             const __bf16* __restrict__ Bm,
                                             int K, int rowBlk, int colBlk,
                                             __bf16* As, __bf16* Bs,
                                             f32x4 acc[4][4]) {
    const int tid  = threadIdx.x;
    const int lane = tid & 63, wid = tid >> 6;
    const int quad = lane >> 4, l16 = lane & 15;
    const int wm = wid >> 1, wn = wid & 1;

    f32x4 z = {0.f, 0.f, 0.f, 0.f};
#pragma unroll
    for (int mi = 0; mi < 4; ++mi)
#pragma unroll
        for (int ni = 0; ni < 4; ++ni) acc[mi][ni] = z;

    for (int k0 = 0; k0 < K; k0 += 64) {
        __syncthreads();
#pragma unroll
        for (int i = 0; i < 4; ++i) {
            int s = i * 256 + tid;
            int row = s >> 3, pc = s & 7;
            int lc = pc ^ (row & 7);
            lds_dma16(A  + (size_t)(rowBlk + row) * K + k0 + lc * 8, As + s * 8);
            lds_dma16(Bm + (size_t)(colBlk + row) * K + k0 + lc * 8, Bs + s * 8);
        }
        __syncthreads();

#pragma unroll
        for (int kc = 0; kc < 2; ++kc) {
            bf16x8 af[4], bfr[4];
#pragma unroll
            for (int mi = 0; mi < 4; ++mi) {
                int row = wm * 64 + mi * 16 + l16;
                int pc = (quad + 4 * kc) ^ (row & 7);
                af[mi] = *(const bf16x8*)(As + row * 64 + pc * 8);
            }
#pragma unroll
            for (int ni = 0; ni < 4; ++ni) {
                int row = wn * 64 + ni * 16 + l16;
                int pc = (quad + 4 * kc) ^ (row & 7);
                bfr[ni] = *(const bf16x8*)(Bs + row * 64 + pc * 8);
            }
#pragma unroll
            for (int mi = 0; mi < 4; ++mi)
#pragma unroll
                for (int ni = 0; ni < 4; ++ni)
                    acc[mi][ni] = MFMA16(af[mi], bfr[ni], acc[mi][ni]);
        }
    }
}

// ---------------- QKV GEMM: X(8192x768) @ Wqkv(2304x768)^T, scatter to Q/K/Vt ----------------
__global__ __launch_bounds__(256) void qkv_gemm(const __bf16* __restrict__ Xb,
                                                const __bf16* __restrict__ Wb,
                                                __bf16* __restrict__ Qb,
                                                __bf16* __restrict__ Kb,
                                                __bf16* __restrict__ Vt) {
    __shared__ __bf16 smem[128 * 128];   // 32 KB: mainloop uses first 16 KB; V-epilogue all
    f32x4 acc[4][4];
    const int rowBlk = blockIdx.x * 128, colBlk = blockIdx.y * 128;
    gemm128_loop(Xb, Wb, CH, rowBlk, colBlk, smem, smem + 128 * 64, acc);

    const int tid = threadIdx.x;
    const int lane = tid & 63, wid = tid >> 6;
    const int quad = lane >> 4, l16 = lane & 15, wm = wid >> 1, wn = wid & 1;
    const int b = rowBlk >> 11, n0 = rowBlk & (SEQ - 1);

    if (colBlk < 2 * CH) {
        const int isK = (colBlk >= CH);
#pragma unroll
        for (int mi = 0; mi < 4; ++mi)
#pragma unroll
            for (int ni = 0; ni < 4; ++ni)
#pragma unroll
                for (int r = 0; r < 4; ++r) {
                    int n = n0 + wm * 64 + mi * 16 + quad * 4 + r;
                    int cc = colBlk - (isK ? CH : 0) + wn * 64 + ni * 16 + l16;
                    int h = cc >> 6, d = cc & 63;
                    size_t idx = (size_t)((b * NH + h) * SEQ + n) * HD + d;
                    float v = acc[mi][ni][r];
                    if (isK) Kb[idx] = (__bf16)v;
                    else     Qb[idx] = (__bf16)(v * QSCALE);
                }
    } else {
        // V: transpose through LDS, write V^T coalesced
        const int vblk = colBlk - 2 * CH;
        __syncthreads();
#pragma unroll
        for (int mi = 0; mi < 4; ++mi)
#pragma unroll
            for (int ni = 0; ni < 4; ++ni)
#pragma unroll
                for (int r = 0; r < 4; ++r) {
                    int rl = wm * 64 + mi * 16 + quad * 4 + r;   // n-local
                    int cl = wn * 64 + ni * 16 + l16;            // d-local
                    smem[cl * 128 + (((rl >> 3) ^ (cl & 15)) << 3) + (rl & 7)] =
                        (__bf16)acc[mi][ni][r];
                }
        __syncthreads();
        const int dl = tid >> 1;
        const int d  = vblk + dl;
        const int h  = d >> 6, dd = d & 63;
        const size_t base = (size_t)((b * NH + h) * HD + dd) * SEQ + n0;
#pragma unroll
        for (int j2 = 0; j2 < 8; ++j2) {
            int j = (tid & 1) * 8 + j2;
            uint4 val = *(const uint4*)(smem + dl * 128 + ((j ^ (dl & 15)) << 3));
            *(uint4*)(Vt + base + j * 8) = val;
        }
    }
}

// ---------------- Flash attention v9: 128-key staging tiles (R8 body x2 per barrier) ---------
// Block = 4 waves, 128 queries. Per iteration: stage 128 keys of K + V^T (32 KB, 8 DMAs)
// behind one barrier pair, then run the proven 64-key body on each sub-tile.
__global__ __launch_bounds__(256, 3) void flash_attn(const __bf16* __restrict__ Qb,
                                                     const __bf16* __restrict__ Kb,
                                                     const __bf16* __restrict__ Vt,
                                                     __bf16* __restrict__ Ab) {
    __shared__ __bf16 smem[16384];       // 32 KB: Ks0|Vs0|Ks1|Vs1 (4KB elements each)
                                         // epilogue reuses first 18 KB as [128][72]

    const int tid  = threadIdx.x;
    const int lane = tid & 63, wid = tid >> 6;
    const int quad = lane >> 4, l16 = lane & 15;

    // XCD-aware decode: blk%8 = XCD; 6 bh x 16 qblk per XCD.
    const int lin  = blockIdx.x;              // 0..767
    const int xcd  = lin & 7, idx = lin >> 3; // idx 0..95
    const int bh   = xcd * 6 + (idx >> 4);    // 0..47
    const int qblk = idx & 15;                // 0..15 (128 queries each)
    const int b    = bh / NH, head = bh - b * NH;

    const int qA = qblk * 128 + wid * 16 + l16;
    const int qB = qA + 64;

    // Q^T B-frags (held whole kernel): lane n=l16=q, k(d) = kcd*32 + quad*8 + j
    bf16x8 qfA[2], qfB[2];
#pragma unroll
    for (int kcd = 0; kcd < 2; ++kcd) {
        qfA[kcd] = *(const bf16x8*)(Qb + (size_t)(bh * SEQ + qA) * HD + kcd * 32 + quad * 8);
        qfB[kcd] = *(const bf16x8*)(Qb + (size_t)(bh * SEQ + qB) * HD + kcd * 32 + quad * 8);
    }

    // key permutation (even/odd groups) for zero-cndmask P exchange
    const int key_e = ((l16 >> 2) << 3) + (l16 & 3);
    const int key_o = ((((l16 >> 2) ^ 1)) << 3) + 4 + (l16 & 3);

    f32x4 otA[4], otB[4];
    f32x4 z = {0.f, 0.f, 0.f, 0.f};
#pragma unroll
    for (int dg = 0; dg < 4; ++dg) { otA[dg] = z; otB[dg] = z; }
    float lA = 0.f, lB = 0.f;

    const __bf16* Kbh = Kb + (size_t)bh * SEQ * HD;
    const __bf16* Vbh = Vt + (size_t)bh * HD * SEQ;

    const int s_row = tid >> 3, s_pc = tid & 7;
    const int s_lc0 = s_pc ^ SWZ(s_row);
    const int s_lc1 = s_pc ^ SWZ(s_row + 32);

// proven R8 64-key body on sub-tile at (Ks, Vs)
#define PROCESS(Ks, Vs)                                                                       \
    do {                                                                                      \
        f32x4 stA[4], stB[4];                                                                 \
        _Pragma("unroll")                                                                     \
        for (int g = 0; g < 4; ++g) { stA[g] = z; stB[g] = z; }                               \
        _Pragma("unroll")                                                                     \
        for (int g = 0; g < 4; ++g) {                                                         \
            const int key = ((g >> 1) << 5) + ((g & 1) ? key_o : key_e);                      \
            _Pragma("unroll")                                                                 \
            for (int kcd = 0; kcd < 2; ++kcd) {                                               \
                int c8 = quad + (kcd << 2);                                                   \
                bf16x8 kf = *(const bf16x8*)((Ks) + key * 64 + ((c8 ^ SWZ(key)) << 3));       \
                stA[g] = MFMA16(kf, qfA[kcd], stA[g]);                                        \
                stB[g] = MFMA16(kf, qfB[kcd], stB[g]);                                        \
            }                                                                                 \
        }                                                                                     \
        bf16x8 pfA[2], pfB[2];                                                                \
        _Pragma("unroll")                                                                     \
        for (int g = 0; g < 4; ++g)                                                           \
            _Pragma("unroll")                                                                 \
            for (int r = 0; r < 4; ++r) {                                                     \
                float p = EXP2(stA[g][r]);                                                    \
                stA[g][r] = p;                                                                \
                lA += p;                                                                      \
            }                                                                                 \
        _Pragma("unroll")                                                                     \
        for (int kk = 0; kk < 2; ++kk) {                                                      \
            unsigned w0 = pack2(stA[2 * kk][0], stA[2 * kk][1]);                              \
            unsigned w1 = pack2(stA[2 * kk][2], stA[2 * kk][3]);                              \
            unsigned x0 = pack2(stA[2 * kk + 1][0], stA[2 * kk + 1][1]);                      \
            unsigned x1 = pack2(stA[2 * kk + 1][2], stA[2 * kk + 1][3]);                      \
            unsigned w2 = (unsigned)__shfl_xor((int)x0, 16, 64);                              \
            unsigned w3 = (unsigned)__shfl_xor((int)x1, 16, 64);                              \
            union { bf16x8 v; unsigned u[4]; } f;                                             \
            f.u[0] = w0; f.u[1] = w1; f.u[2] = w2; f.u[3] = w3;                               \
            pfA[kk] = f.v;                                                                    \
        }                                                                                     \
        _Pragma("unroll")                                                                     \
        for (int g = 0; g < 4; ++g)                                                           \
            _Pragma("unroll")                                                                 \
            for (int r = 0; r < 4; ++r) {                                                     \
                float p = EXP2(stB[g][r]);                                                    \
                stB[g][r] = p;                                                                \
                lB += p;                                                                      \
            }                                                                                 \
        _Pragma("unroll")                                                                     \
        for (int kk = 0; kk < 2; ++kk) {                                                      \
            unsigned w0 = pack2(stB[2 * kk][0], stB[2 * kk][1]);                              \
            unsigned w1 = pack2(stB[2 * kk][2], stB[2 * kk][3]);                              \
            unsigned x0 = pack2(stB[2 * kk + 1][0], stB[2 * kk + 1][1]);                      \
            unsigned x1 = pack2(stB[2 * kk + 1][2], stB[2 * kk + 1][3]);                      \
            unsigned w2 = (unsigned)__shfl_xor((int)x0, 16, 64);                              \
            unsigned w3 = (unsigned)__shfl_xor((int)x1, 16, 64);                              \
            union { bf16x8 v; unsigned u[4]; } f;                                             \
            f.u[0] = w0; f.u[1] = w1; f.u[2] = w2; f.u[3] = w3;                               \
            pfB[kk] = f.v;                                                                    \
        }                                                                                     \
        _Pragma("unroll")                                                                     \
        for (int dg = 0; dg < 4; ++dg)                                                        \
            _Pragma("unroll")                                                                 \
            for (int kk = 0; kk < 2; ++kk) {                                                  \
                int row = (dg << 4) + l16;                                                    \
                int c8 = quad + (kk << 2);                                                    \
                bf16x8 vf = *(const bf16x8*)((Vs) + row * 64 + ((c8 ^ SWZ(row)) << 3));       \
                otA[dg] = MFMA16(vf, pfA[kk], otA[dg]);                                       \
                otB[dg] = MFMA16(vf, pfB[kk], otB[dg]);                                       \
            }                                                                                 \
    } while (0)

    for (int kb = 0; kb < SEQ / 128; ++kb) {
        const int kbase = kb * 128;
        __syncthreads();   // prior-iteration LDS readers done
        // sub-tile 0: keys kbase..kbase+63
        lds_dma16(Kbh + (size_t)(kbase + s_row) * HD + s_lc0 * 8,            smem + tid * 8);
        lds_dma16(Kbh + (size_t)(kbase + s_row + 32) * HD + s_lc1 * 8,       smem + 2048 + tid * 8);
        lds_dma16(Vbh + (size_t)s_row * SEQ + kbase + s_lc0 * 8,             smem + 4096 + tid * 8);
        lds_dma16(Vbh + (size_t)(s_row + 32) * SEQ + kbase + s_lc1 * 8,      smem + 6144 + tid * 8);
        // sub-tile 1: keys kbase+64..kbase+127
        lds_dma16(Kbh + (size_t)(kbase + 64 + s_row) * HD + s_lc0 * 8,       smem + 8192 + tid * 8);
        lds_dma16(Kbh + (size_t)(kbase + 96 + s_row) * HD + s_lc1 * 8,       smem + 10240 + tid * 8);
        lds_dma16(Vbh + (size_t)s_row * SEQ + kbase + 64 + s_lc0 * 8,        smem + 12288 + tid * 8);
        lds_dma16(Vbh + (size_t)(s_row + 32) * SEQ + kbase + 64 + s_lc1 * 8, smem + 14336 + tid * 8);
        __syncthreads();   // drains dma

        PROCESS(smem, smem + 4096);
        PROCESS(smem + 8192, smem + 12288);
    }
#undef PROCESS

    lA += __shfl_xor(lA, 16, 64);
    lA += __shfl_xor(lA, 32, 64);
    lB += __shfl_xor(lB, 16, 64);
    lB += __shfl_xor(lB, 32, 64);
    const float rA = 1.f / lA, rB = 1.f / lB;

    __syncthreads();   // reuse smem as [128][72] for O transpose
    __bf16 (*Ob)[72] = (__bf16(*)[72])smem;
#pragma unroll
    for (int dg = 0; dg < 4; ++dg)
#pragma unroll
        for (int r = 0; r < 4; ++r) {
            int d = (dg << 4) + (quad << 2) + r;
            Ob[wid * 16 + l16][d]      = (__bf16)(otA[dg][r] * rA);
            Ob[64 + wid * 16 + l16][d] = (__bf16)(otB[dg][r] * rB);
        }
    __syncthreads();
    {
        const int row = tid >> 1, c0 = (tid & 1) * 32;
        __bf16* dst = Ab + (size_t)(b * SEQ + qblk * 128 + row) * CH + head * HD + c0;
#pragma unroll
        for (int j = 0; j < 4; ++j)
            *(uint4*)(dst + j * 8) = *(const uint4*)(&Ob[row][c0 + j * 8]);
    }
}

// ---------------- Projection GEMM: Attn(8192x768) @ proj_w(768x768)^T + bias ----------------
__global__ __launch_bounds__(256) void proj_gemm(const __bf16* __restrict__ Ab,
                                                 const __bf16* __restrict__ Pw,
                                                 const float* __restrict__ bias,
                                                 float* __restrict__ out) {
    __shared__ __bf16 As[128 * 64];
    __shared__ __bf16 Bs[128 * 64];
    f32x4 acc[4][4];
    const int rowBlk = blockIdx.x * 128, colBlk = blockIdx.y * 128;
    gemm128_loop(Ab, Pw, CH, rowBlk, colBlk, As, Bs, acc);

    const int lane = threadIdx.x & 63, wid = threadIdx.x >> 6;
    const int quad = lane >> 4, l16 = lane & 15, wm = wid >> 1, wn = wid & 1;
#pragma unroll
    for (int mi = 0; mi < 4; ++mi)
#pragma unroll
        for (int ni = 0; ni < 4; ++ni)
#pragma unroll
            for (int r = 0; r < 4; ++r) {
                int row = rowBlk + wm * 64 + mi * 16 + quad * 4 + r;
                int col = colBlk + wn * 64 + ni * 16 + l16;
                out[(size_t)row * CH + col] = acc[mi][ni][r] + bias[col];
            }
}

extern "C" void kernel_launch(void* const* d_in, const int* in_sizes, int n_in,
                              void* d_out, int out_size, void* d_ws, size_t ws_size,
                              hipStream_t stream) {
    const float* x      = (const float*)d_in[0];
    const float* qkv_w  = (const float*)d_in[1];
    const float* proj_w = (const float*)d_in[2];
    const float* proj_b = (const float*)d_in[3];
    float* out = (float*)d_out;

    char* ws = (char*)d_ws;
    const size_t nX = (size_t)B_SZ * SEQ * CH;
    const size_t nW = (size_t)3 * CH * CH;
    const size_t nP = (size_t)CH * CH;
    const size_t nQ = (size_t)B_SZ * NH * SEQ * HD;

    __bf16* Xb = (__bf16*)(ws);
    __bf16* Wb = (__bf16*)(ws + 2 * nX);
    __bf16* Pw = (__bf16*)(ws + 2 * (nX + nW));
    __bf16* Qb = (__bf16*)(ws + 2 * (nX + nW + nP));
    __bf16* Kb = (__bf16*)(ws + 2 * (nX + nW + nP + nQ));
    __bf16* Vt = (__bf16*)(ws + 2 * (nX + nW + nP + 2 * nQ));
    __bf16* Ab = (__bf16*)(ws + 2 * (nX + nW + nP + 3 * nQ));

    convert_all<<<NBLK_X + NBLK_W + NBLK_P, 256, 0, stream>>>(x, qkv_w, proj_w, Xb, Wb, Pw);

    qkv_gemm<<<dim3((B_SZ * SEQ) / 128, (3 * CH) / 128), 256, 0, stream>>>(Xb, Wb, Qb, Kb, Vt);

    flash_attn<<<768, 256, 0, stream>>>(Qb, Kb, Vt, Ab);

    proj_gemm<<<dim3((B_SZ * SEQ) / 128, CH / 128), 256, 0, stream>>>(Ab, Pw, proj_b, out);
}